// Round 4
// baseline (1811.637 us; speedup 1.0000x reference)
//
#include <hip/hip_runtime.h>

// Murray single-area 2-unit RNN scan — lane-pair split + NB=4 chain ILP.
//
// B=8192 independent sequential chains of T*spb=8000 sub-steps. R1 (1 chain
// per lane pair) measured ~121 cy/sub-step with only ~38 cy of issue
// occupancy -> dependency-latency-bound at 1 wave/SIMD. This version gives
// each lane NB=4 INDEPENDENT chains (unit u of chains {n*(B/NB) + i});
// in-order issue interleaves the 4 bodies and fills the latency bubbles.
// Expected ~38 cy/chain-sub-step -> ~150-190 us dispatch.
//
// Lane mapping: lane pair (2i, 2i+1) = units 0/1 of the same chain set; the
// cross-unit coupling s_other is exchanged per sub-step with one full-rate
// DPP quad_perm swap (0xB1).
//
// Implementation deliberately flat (R2/R3 container failures were likely
// infra, but defensively): no pointer arrays, one run_loop body, simple
// 2-deep input pipeline (load bin t+2 while computing bin t; 2-bin lookahead
// ~1200 cy > ~900 cy HBM miss latency; a 64B line covers 8 bins per lane).
//
// Numerics identical to the verified R0/R1 kernels:
//   x = -C*log2e * act;  rate = INVC * (x * rcp(1-exp2(x))),  INVC = -ln2/C
//   window guard |x| < 1e-5 -> scaled rate = -log2e (limit 1/C), NOT exact==0:
//   hw exp2 can round to 1.0 for tiny x -> d=0 -> rcp=inf -> NaN cascade.

#define AF    270.0f
#define BF    108.0f
#define CF    0.154f
#define DTF   0.001f
#define I0F   0.334f
#define TAUF  0.06f
#define GAMF  0.641f
#define LOG2EF 1.44269504088896340736f
#define LN2F   0.69314718055994530942f

#if __has_builtin(__builtin_amdgcn_exp2f)
#define EXP2F(x) __builtin_amdgcn_exp2f(x)
#else
#define EXP2F(x) exp2f(x)
#endif

#if __has_builtin(__builtin_amdgcn_rcpf)
#define RCPF(x) __builtin_amdgcn_rcpf(x)
#else
#define RCPF(x) (1.0f / (x))
#endif

// Swap adjacent lanes (0<->1, 2<->3, ...): DPP quad_perm [1,0,3,2] = 0xB1.
__device__ __forceinline__ float dpp_swap1(float v) {
  return __int_as_float(
      __builtin_amdgcn_mov_dpp(__float_as_int(v), 0xB1, 0xF, 0xF, true));
}

struct Consts {
  float Xs, Xo;   // coeffs of s_self / s_other in x (A and -C*log2e folded in)
  float P, Q;     // x contribution of input: xq = P*in + Q
  float K1;       // 1 - sub_dt/TAU
  float K2C;      // sub_dt*GAMMA*INVC (applied to (1-s) * x/denom)
  float INVC;     // rate = INVC * r2 ; INVC = -ln2/C
};

// One sub-step for THIS lane's unit of one chain.
__device__ __forceinline__ void substep(const Consts& c, float xq,
                                        float& s, float& r2) {
  float so = dpp_swap1(s);          // partner unit's state
  float p  = fmaf(c.Xs, s, xq);     // independent of the dpp -> overlaps it
  float x  = fmaf(c.Xo, so, p);
  float e  = EXP2F(x);
  float d  = 1.0f - e;
  float t  = x * RCPF(d);
  // near act==0: rate -> 1/C  <=>  scaled r2 -> -log2e (window, not ==0)
  r2 = (__builtin_fabsf(x) < 1e-5f) ? -LOG2EF : t;
  float u = fmaf(-s, r2, r2);       // (1-s)*r2
  s = fmaf(c.K2C, u, c.K1 * s);
}

template <int NB>
__global__ __launch_bounds__(64, 1)
void murray_kernel(const float* __restrict__ inp, const float* __restrict__ h0,
                   const float* __restrict__ Jm, const int* __restrict__ spb_p,
                   float* __restrict__ out, int B, int T) {
  const int glane = blockIdx.x * 64 + threadIdx.x;
  const int i = glane >> 1;     // lane-pair index
  const int u = glane & 1;      // unit within the chain
  const int Bp = B / NB;        // chains per stream slot (host ensures B%NB==0)
  if (i >= Bp) return;
  const int spb = *spb_p;

  // current_j = s0*J[0][j] + s1*J[1][j] + I0 + in_j ; J row-major in Jm.
  const float Jself = u ? Jm[3] : Jm[0];
  const float Joth  = u ? Jm[1] : Jm[2];
  const float sub_dt = DTF / (float)spb;
  const float NC = -CF * LOG2EF;  // fold exp -> exp2

  Consts c;
  c.Xs = NC * AF * Jself;
  c.Xo = NC * AF * Joth;
  c.P  = NC * AF;
  c.Q  = NC * fmaf(AF, I0F, -BF);
  c.K1 = 1.0f - sub_dt / TAUF;
  c.INVC = -LN2F / CF;
  c.K2C = sub_dt * GAMF * c.INVC;

  // Per-chain element offsets into the [*,T,2] blocks (constant after unroll).
  const size_t row = (size_t)(2 * T);
  const size_t rateOfs = (size_t)B * row;        // rates block starts here
  size_t base[NB];                               // chain n: cB*row + u
  float s[NB];
#pragma unroll
  for (int n = 0; n < NB; ++n) {
    const int cB = n * Bp + i;
    base[n] = (size_t)cB * row + (size_t)u;
    s[n] = h0[2 * cB + u];
  }

  const int Tm1 = T - 1;
  // 2-deep input pipeline: b0 = bin t, b1 = bin t+1; load t+2 during compute.
  float b0[NB], b1[NB];
#pragma unroll
  for (int n = 0; n < NB; ++n) {
    b0[n] = inp[base[n]];
    b1[n] = inp[base[n] + (size_t)(2 * (Tm1 > 0 ? 1 : 0))];
  }

  for (int t = 0; t < T; ++t) {
    const int tn = (t + 2 < Tm1 ? t + 2 : Tm1);
    float nxt[NB];
#pragma unroll
    for (int n = 0; n < NB; ++n) nxt[n] = inp[base[n] + (size_t)(2 * tn)];

    float xq[NB], r2[NB];
#pragma unroll
    for (int n = 0; n < NB; ++n) {
      xq[n] = fmaf(c.P, b0[n], c.Q);
      r2[n] = -LOG2EF;
    }
    if (spb == 4) {
#pragma unroll
      for (int k = 0; k < 4; ++k)
#pragma unroll
        for (int n = 0; n < NB; ++n) substep(c, xq[n], s[n], r2[n]);
    } else {
      for (int k = 0; k < spb; ++k)
#pragma unroll
        for (int n = 0; n < NB; ++n) substep(c, xq[n], s[n], r2[n]);
    }

    const size_t to = (size_t)(2 * t);
#pragma unroll
    for (int n = 0; n < NB; ++n) {
      out[base[n] + to] = s[n];                      // states [B,T,2]
      out[rateOfs + base[n] + to] = c.INVC * r2[n];  // rates  [B,T,2]
      b0[n] = b1[n];
      b1[n] = nxt[n];
    }
  }

  // final [1,B,2] after both blocks
#pragma unroll
  for (int n = 0; n < NB; ++n) {
    const int cB = n * Bp + i;
    out[rateOfs * 2 + (size_t)(2 * cB + u)] = s[n];
  }
}

extern "C" void kernel_launch(void* const* d_in, const int* in_sizes, int n_in,
                              void* d_out, int out_size, void* d_ws, size_t ws_size,
                              hipStream_t stream) {
  const float* inp = (const float*)d_in[0];
  const float* h0  = (const float*)d_in[1];
  const float* J   = (const float*)d_in[2];
  const int* spb   = (const int*)d_in[3];
  float* out = (float*)d_out;

  const int B = in_sizes[1] / 2;            // h0 is [1,B,2]
  const int T = in_sizes[0] / (2 * B);      // input is [B,T,2]

  const int NB = (B % 4 == 0) ? 4 : ((B % 2 == 0) ? 2 : 1);
  const int threads = 2 * (B / NB);         // one lane per (stream-slot, unit)
  const int blocks = (threads + 63) / 64;

  if (NB == 4) {
    murray_kernel<4><<<blocks, 64, 0, stream>>>(inp, h0, J, spb, out, B, T);
  } else if (NB == 2) {
    murray_kernel<2><<<blocks, 64, 0, stream>>>(inp, h0, J, spb, out, B, T);
  } else {
    murray_kernel<1><<<blocks, 64, 0, stream>>>(inp, h0, J, spb, out, B, T);
  }
}

// Round 6
// 659.871 us; speedup vs baseline: 2.7454x; 2.7454x over previous
//
#include <hip/hip_runtime.h>

// Murray single-area 2-unit RNN scan — lane-pair split + x-recurrence.
//
// R4 post-mortem: NB=4 chain-ILP spilled to scratch (VGPR capped at 32,
// VALUBusy 2.8%, 1557us) AND the ILP math was wrong anyway: per-substep issue
// (~36cy) x4 chains exceeds the latency-bound 121cy of one chain. Wall time =
// per-wave serial chain latency, period. So: keep the verified R1 structure
// (403us) and shorten the dependency CYCLE instead.
//
// R1 cycle (10 links): s'->dpp->fma->fma(x)->exp2->sub->rcp->mul->cndmask->
// fma(u)->fma(s'). Substituting s'=K1*s+K2C*u into x'=Xs*s'+Xo*so'+xq gives
//   x' = K1*x + (1-K1)*xq + (Xs*K2C)*u + (Xo*K2C)*dpp(u)
// removing s' from the x-path (9 links; fma(K1,x,xq1) and the |x| cmp run in
// parallel with exp2; the dpp is separated from its producer by independent
// fmas so its hazard wait-states overlap). s is still updated exactly as
// before; x drift is contractive (K1~0.999) and bounded ~1e-5 rel.
//
// Numerics: x = -C*log2e * act; rate = INVC * (x * rcp(1-exp2(x))).
// Window guard |x| < 1e-5 -> scaled rate = -log2e (limit 1/C), NOT exact==0:
// hw exp2 can round to 1.0 for tiny x -> d=0 -> rcp=inf -> NaN cascade.

#define AF    270.0f
#define BF    108.0f
#define CF    0.154f
#define DTF   0.001f
#define I0F   0.334f
#define TAUF  0.06f
#define GAMF  0.641f
#define LOG2EF 1.44269504088896340736f
#define LN2F   0.69314718055994530942f

#if __has_builtin(__builtin_amdgcn_exp2f)
#define EXP2F(x) __builtin_amdgcn_exp2f(x)
#else
#define EXP2F(x) exp2f(x)
#endif

#if __has_builtin(__builtin_amdgcn_rcpf)
#define RCPF(x) __builtin_amdgcn_rcpf(x)
#else
#define RCPF(x) (1.0f / (x))
#endif

// Swap adjacent lanes (0<->1, 2<->3, ...): DPP quad_perm [1,0,3,2] = 0xB1.
__device__ __forceinline__ float dpp_swap1(float v) {
  return __int_as_float(
      __builtin_amdgcn_mov_dpp(__float_as_int(v), 0xB1, 0xF, 0xF, true));
}

struct Consts {
  float Xs, Xo;    // coeffs of s_self/s_other in x (x init only)
  float SXU, SXO;  // Xs*K2C, Xo*K2C  (x-recurrence coefficients)
  float P, Q;      // xq = P*in + Q
  float K1, R1T;   // K1 = 1 - R1T ; R1T = sub_dt/TAU
  float K2C;       // sub_dt*GAMMA*INVC
  float INVC;      // rate = INVC * r2 ; INVC = -ln2/C
};

// One sub-step. Carries (s, x); r2 = scaled rate of THIS sub-step.
__device__ __forceinline__ void substep(const Consts& c, float xq1,
                                        float& s, float& x, float& r2) {
  float e  = EXP2F(x);                 // chain
  float d  = 1.0f - e;                 // chain
  float t  = x * RCPF(d);              // chain (rcp + mul)
  // cmp runs in parallel with exp2 (x available); cndmask is on-chain
  r2 = (__builtin_fabsf(x) < 1e-5f) ? -LOG2EF : t;
  float k1s = c.K1 * s;                // off-chain (old s, runs early)
  float inner = fmaf(c.K1, x, xq1);    // off-chain (old x, runs early)
  float u  = fmaf(-s, r2, r2);         // (1-s)*r2         chain
  s = fmaf(c.K2C, u, k1s);             // off-chain wrt x-cycle
  float du = dpp_swap1(u);             // chain (indep instrs follow producer)
  float m1 = fmaf(c.SXU, u, inner);    // chain-parallel
  x = fmaf(c.SXO, du, m1);             // chain
}

// One bin: spb sub-steps; rt = rate of the LAST sub-step.
template <int SPB>
__device__ __forceinline__ void bin(const Consts& c, int spb, float in,
                                    float& s, float& x, float& inprev,
                                    float& rt) {
  // bin-boundary xq shift: x carries +xq_old; exact delta is P*(in-inprev)
  x = fmaf(c.P, in - inprev, x);
  inprev = in;
  float xq1 = c.R1T * fmaf(c.P, in, c.Q);  // (1-K1)*xq
  float r2 = -LOG2EF;
  if (SPB > 0) {
#pragma unroll
    for (int k = 0; k < SPB; ++k) substep(c, xq1, s, x, r2);
  } else {
    for (int k = 0; k < spb; ++k) substep(c, xq1, s, x, r2);
  }
  rt = c.INVC * r2;
}

template <int SPB>
__device__ __forceinline__ void run_loop(const Consts& c, int spb, int T,
                                         const float* __restrict__ ip,
                                         float* __restrict__ sp,
                                         float* __restrict__ rp,
                                         float& s, float& x, float& inprev) {
  // Register prefetch ring, PF bins deep (statically indexed, fully unrolled).
  // One 4B load per bin; a 64B line covers 8 bins of the lane pair; the
  // PF-deep lead (~PF*4*~100cy) hides the ~900cy HBM miss.
  constexpr int PF = 8;
  const int Tm1 = T - 1;
  float buf[PF];
#pragma unroll
  for (int i = 0; i < PF; ++i) buf[i] = ip[2 * (i < Tm1 ? i : Tm1)];
  int t0 = 0;
  for (; t0 + PF <= T; t0 += PF) {
#pragma unroll
    for (int j = 0; j < PF; ++j) {
      // issue next-chunk load early (clamped; clamped values never consumed)
      const int tn = (t0 + PF + j < Tm1 ? t0 + PF + j : Tm1);
      float nxt = ip[2 * tn];
      float rt;
      bin<SPB>(c, spb, buf[j], s, x, inprev, rt);
      const int t = t0 + j;
      sp[2 * t] = s;
      rp[2 * t] = rt;
      buf[j] = nxt;
    }
  }
  for (; t0 < T; ++t0) {  // tail (T % PF)
    float rt;
    bin<SPB>(c, spb, ip[2 * t0], s, x, inprev, rt);
    sp[2 * t0] = s;
    rp[2 * t0] = rt;
  }
}

__global__ __launch_bounds__(64, 1)
void murray_kernel(const float* __restrict__ inp, const float* __restrict__ h0,
                   const float* __restrict__ Jm, const int* __restrict__ spb_p,
                   float* __restrict__ out, int B, int T) {
  const int tid = blockIdx.x * 64 + threadIdx.x;
  const int cB = tid >> 1;      // chain (batch element)
  const int u  = tid & 1;       // unit within the chain
  if (cB >= B) return;
  const int spb = *spb_p;

  // current_j = s0*J[0][j] + s1*J[1][j] + I0 + in_j ; J row-major in Jm.
  const float Jself = u ? Jm[3] : Jm[0];
  const float Joth  = u ? Jm[1] : Jm[2];
  const float sub_dt = DTF / (float)spb;
  const float NC = -CF * LOG2EF;  // fold exp -> exp2

  Consts c;
  c.Xs  = NC * AF * Jself;
  c.Xo  = NC * AF * Joth;
  c.P   = NC * AF;
  c.Q   = NC * fmaf(AF, I0F, -BF);
  c.R1T = sub_dt / TAUF;
  c.K1  = 1.0f - c.R1T;
  c.INVC = -LN2F / CF;
  c.K2C = sub_dt * GAMF * c.INVC;
  c.SXU = c.Xs * c.K2C;
  c.SXO = c.Xo * c.K2C;

  float s = h0[2 * cB + u];
  // x init with inprev = 0: x = Xs*s + Xo*so + Q; first bin's shift adds P*in.
  float so = dpp_swap1(s);
  float x  = fmaf(c.Xs, s, fmaf(c.Xo, so, c.Q));
  float inprev = 0.0f;

  const size_t row = (size_t)(2 * T);
  const float* ip = inp + (size_t)cB * row + u;
  float* sp = out + (size_t)cB * row + u;                       // states [B,T,2]
  float* rp = out + (size_t)B * row + (size_t)cB * row + u;     // rates  [B,T,2]
  float* fp = out + (size_t)B * row * 2 + (size_t)(2 * cB + u); // final  [1,B,2]

  if (spb == 4) {
    run_loop<4>(c, spb, T, ip, sp, rp, s, x, inprev);
  } else {
    run_loop<0>(c, spb, T, ip, sp, rp, s, x, inprev);
  }

  fp[0] = s;
}

extern "C" void kernel_launch(void* const* d_in, const int* in_sizes, int n_in,
                              void* d_out, int out_size, void* d_ws, size_t ws_size,
                              hipStream_t stream) {
  const float* inp = (const float*)d_in[0];
  const float* h0  = (const float*)d_in[1];
  const float* J   = (const float*)d_in[2];
  const int* spb   = (const int*)d_in[3];
  float* out = (float*)d_out;

  const int B = in_sizes[1] / 2;            // h0 is [1,B,2]
  const int T = in_sizes[0] / (2 * B);      // input is [B,T,2]
  const int threads = 2 * B;                // one lane per (chain, unit)
  const int blocks = (threads + 63) / 64;

  murray_kernel<<<blocks, 64, 0, stream>>>(inp, h0, J, spb, out, B, T);
}